// Round 1
// 133.291 us; speedup vs baseline: 1.1185x; 1.1185x over previous
//
#include <hip/hip_runtime.h>

#define BS 32
#define NA 512
#define ID 128
#define NH 8
#define HD 64
#define NHD 512   // NH*HD
#define NEG 0.2f
#define NC 32     // scalar chunk count (G=16) for zps/znp
#define CH 16
#define NW 8      // waves per k2 block (512 threads)

// K1: h_prime = h @ W (fp32). Block = 16 rows x 512 cols, 4 waves: wave w has
// rows (w>>1)*8..+7 (WAVE-UNIFORM -> A via s_load, zero LDS/DS traffic) and
// cols (w&1)*256 + 4*lane (dense 1KB W loads). Unchanged from prior session.
__global__ __launch_bounds__(256) void k1_gemm(
    const float* __restrict__ h, const float* __restrict__ W,
    const float* __restrict__ att, float* __restrict__ hp,
    float* __restrict__ s_out, float* __restrict__ t_out) {
  int blk = blockIdx.x;
  int b = blk >> 5;
  int n0 = (blk & 31) * 16;
  int t = threadIdx.x;
  int lane = t & 63, w = t >> 6;
  int r0 = __builtin_amdgcn_readfirstlane((w >> 1) * 8);   // 0 or 8
  int chalf = __builtin_amdgcn_readfirstlane(w & 1);
  int col = chalf * 256 + lane * 4;
  int head = col >> 6;
  int d0 = col & 63;
  const float* arow = h + ((size_t)b * NA + n0 + r0) * ID;  // uniform base
  const float* wptr = W + col;

  float4 a0c = {0,0,0,0}, a1c = {0,0,0,0}, a2c = {0,0,0,0}, a3c = {0,0,0,0};
  float4 a4c = {0,0,0,0}, a5c = {0,0,0,0}, a6c = {0,0,0,0}, a7c = {0,0,0,0};

#define K1_ROW(I, C, KK)                                                      \
  { float a_ = arow[(I) * ID + kc + (KK)];                                    \
    C.x += a_ * wv.x; C.y += a_ * wv.y; C.z += a_ * wv.z; C.w += a_ * wv.w; }
  #pragma unroll 1
  for (int kc = 0; kc < ID; kc += 8) {
    #pragma unroll
    for (int kk = 0; kk < 8; ++kk) {
      float4 wv = *(const float4*)(wptr + (size_t)(kc + kk) * NHD);
      K1_ROW(0, a0c, kk) K1_ROW(1, a1c, kk) K1_ROW(2, a2c, kk)
      K1_ROW(3, a3c, kk) K1_ROW(4, a4c, kk) K1_ROW(5, a5c, kk)
      K1_ROW(6, a6c, kk) K1_ROW(7, a7c, kk)
    }
  }
#undef K1_ROW
  {
    size_t off = ((((size_t)b * NH + head) * NA) + (n0 + r0)) * HD + d0;
    *(float4*)(hp + off) = a0c; off += HD;
    *(float4*)(hp + off) = a1c; off += HD;
    *(float4*)(hp + off) = a2c; off += HD;
    *(float4*)(hp + off) = a3c; off += HD;
    *(float4*)(hp + off) = a4c; off += HD;
    *(float4*)(hp + off) = a5c; off += HD;
    *(float4*)(hp + off) = a6c; off += HD;
    *(float4*)(hp + off) = a7c;
  }
  {
    float4 as4 = *(const float4*)(att + head * 128 + d0);
    float4 ad4 = *(const float4*)(att + head * 128 + 64 + d0);
#define DOT4(C, A) ((C).x*(A).x + (C).y*(A).y + (C).z*(A).z + (C).w*(A).w)
    float sp0 = DOT4(a0c, as4), tp0 = DOT4(a0c, ad4);
    float sp1 = DOT4(a1c, as4), tp1 = DOT4(a1c, ad4);
    float sp2 = DOT4(a2c, as4), tp2 = DOT4(a2c, ad4);
    float sp3 = DOT4(a3c, as4), tp3 = DOT4(a3c, ad4);
    float sp4 = DOT4(a4c, as4), tp4 = DOT4(a4c, ad4);
    float sp5 = DOT4(a5c, as4), tp5 = DOT4(a5c, ad4);
    float sp6 = DOT4(a6c, as4), tp6 = DOT4(a6c, ad4);
    float sp7 = DOT4(a7c, as4), tp7 = DOT4(a7c, ad4);
#undef DOT4
    #pragma unroll
    for (int m = 1; m < 16; m <<= 1) {
      sp0 += __shfl_xor(sp0, m, 64); tp0 += __shfl_xor(tp0, m, 64);
      sp1 += __shfl_xor(sp1, m, 64); tp1 += __shfl_xor(tp1, m, 64);
      sp2 += __shfl_xor(sp2, m, 64); tp2 += __shfl_xor(tp2, m, 64);
      sp3 += __shfl_xor(sp3, m, 64); tp3 += __shfl_xor(tp3, m, 64);
      sp4 += __shfl_xor(sp4, m, 64); tp4 += __shfl_xor(tp4, m, 64);
      sp5 += __shfl_xor(sp5, m, 64); tp5 += __shfl_xor(tp5, m, 64);
      sp6 += __shfl_xor(sp6, m, 64); tp6 += __shfl_xor(tp6, m, 64);
      sp7 += __shfl_xor(sp7, m, 64); tp7 += __shfl_xor(tp7, m, 64);
    }
    int g16 = lane & 15;
    int rsel = g16 & 7;
    float sv_ = rsel == 0 ? sp0 : rsel == 1 ? sp1 : rsel == 2 ? sp2 :
                rsel == 3 ? sp3 : rsel == 4 ? sp4 : rsel == 5 ? sp5 :
                rsel == 6 ? sp6 : sp7;
    float tv_ = rsel == 0 ? tp0 : rsel == 1 ? tp1 : rsel == 2 ? tp2 :
                rsel == 3 ? tp3 : rsel == 4 ? tp4 : rsel == 5 ? tp5 :
                rsel == 6 ? tp6 : tp7;
    size_t off = (((size_t)b * NH + head) * NA) + n0 + r0 + rsel;
    if (g16 < 8) s_out[off] = sv_;
    else         t_out[off] = tv_;
  }
}

// K2 (fused): per (b,h) block of 512 threads.
//  - dual hybrid bitonic sort: t ascending AND s ascending (with orig indices).
//  - wave w owns sorted-t rows [64w,64w+64): loads its 64 V rows ONCE into a
//    fully-unrolled register array vreg[64] (static indices only), computing
//    wave-local weighted sums for the cross-wave scan seeds.
//  - js is monotone non-increasing over s-ranks, so rows querying sorted
//    position j form a contiguous rank interval [E[j], E[j-1]); E[] built with
//    one binary search per rank.
//  - single ascending sweep per wave emits FINISHED output rows inline:
//      sufP[j] maintained subtractively from the wave suffix seed (safe: wp is
//      monotone increasing in sorted order, so the suffix is dominated by
//      never-subtracted terms), preN[j] maintained additively (exact prefix).
//  - NO global tables, NO rinfo, NO second apply kernel: global traffic is
//    s,t (1 MB) + V once (33.5 MB) + out (33.5 MB).
__global__ __launch_bounds__(512, 2) void k2_fused(
    const float* __restrict__ hp, const float* __restrict__ s_g,
    const float* __restrict__ t_g, float* __restrict__ out) {
  __shared__ float tv[NA]; __shared__ int tpm[NA];
  __shared__ float sv[NA]; __shared__ int spm[NA];
  __shared__ float wp[NA]; __shared__ float wn[NA];
  __shared__ float rawP8[NW * 64]; __shared__ float rawN8[NW * 64];
  __shared__ float sufPc[(NW + 1) * 64]; __shared__ float preNc[(NW + 1) * 64];
  __shared__ float zps[NA + 1]; __shared__ float znp[NA + 1];
  __shared__ float szP[NC]; __shared__ float szN[NC];
  __shared__ float sufZ[NC + 1]; __shared__ float preZ[NC + 1];
  __shared__ float4 abi[NA];   // {A, B, 1/den, orig_row} per s-rank
  __shared__ int jsr[NA];      // js per s-rank (non-increasing)
  __shared__ int Earr[NA];     // E[j] = first rank with js <= j

  int bh = blockIdx.x;
  int t = threadIdx.x;
  int lane = t & 63, w = t >> 6;
  const float* vbase = hp + (size_t)bh * NA * HD;

  // ---- dual hybrid bitonic sort (t asc, s asc), value+index in regs ----
  float vt = t_g[(size_t)bh * NA + t]; int it = t;
  float vs = s_g[(size_t)bh * NA + t]; int is_ = t;
  for (int size = 2; size <= NA; size <<= 1) {
    bool dirAsc = ((t & size) == 0);
    for (int stride = size >> 1; stride > 0; stride >>= 1) {
      float pt, ps; int pit, pis;
      if (stride >= 64) {
        tv[t] = vt; tpm[t] = it; sv[t] = vs; spm[t] = is_;
        __syncthreads();
        pt = tv[t ^ stride]; pit = tpm[t ^ stride];
        ps = sv[t ^ stride]; pis = spm[t ^ stride];
        __syncthreads();
      } else {
        pt = __shfl_xor(vt, stride, 64); pit = __shfl_xor(it, stride, 64);
        ps = __shfl_xor(vs, stride, 64); pis = __shfl_xor(is_, stride, 64);
      }
      bool mn = (((t & stride) == 0) == dirAsc);
      if (mn ? (pt < vt) : (pt > vt)) { vt = pt; it = pit; }
      if (mn ? (ps < vs) : (ps > vs)) { vs = ps; is_ = pis; }
    }
  }
  tv[t] = vt; tpm[t] = it; sv[t] = vs; spm[t] = is_;
  __syncthreads();

  float cmax = fmaxf(tv[NA - 1], 0.f);
  float amax = fmaxf(sv[NA - 1], 0.f);
  wp[t] = __expf(vt - cmax);
  wn[t] = __expf(NEG * vt - cmax);
  __syncthreads();

  // ---- phase A: V rows -> registers, wave-local weighted sums ----
  float vreg[64];
  {
    float aP = 0.f, aN = 0.f;
    #pragma unroll
    for (int jj = 0; jj < 64; ++jj) {
      int j = (w << 6) + jj;
      float vv = vbase[(size_t)tpm[j] * HD + lane];
      vreg[jj] = vv;
      aP += wp[j] * vv;
      aN += wn[j] * vv;
    }
    rawP8[(w << 6) + lane] = aP;
    rawN8[(w << 6) + lane] = aN;
  }
  __syncthreads();

  // ---- cross-wave scans (vector, G=64) + scalar chunk sums (G=16) ----
  if (t < 64) {
    int d = t; float run = 0.f;
    sufPc[NW * 64 + d] = 0.f;
    for (int ww = NW - 1; ww >= 0; --ww) {
      run += rawP8[ww * 64 + d]; sufPc[ww * 64 + d] = run;
    }
  } else if (t < 128) {
    int d = t - 64; float run = 0.f;
    for (int ww = 0; ww <= NW; ++ww) {
      preNc[ww * 64 + d] = run;
      if (ww < NW) run += rawN8[ww * 64 + d];
    }
  } else if (t < 160) {
    int c = t - 128; float a = 0.f;
    for (int j = c * CH; j < c * CH + CH; ++j) a += wp[j];
    szP[c] = a;
  } else if (t < 192) {
    int c = t - 160; float a = 0.f;
    for (int j = c * CH; j < c * CH + CH; ++j) a += wn[j];
    szN[c] = a;
  }
  __syncthreads();

  if (t == 0) {
    float run = 0.f; sufZ[NC] = 0.f;
    for (int cc = NC - 1; cc >= 0; --cc) { run += szP[cc]; sufZ[cc] = run; }
  } else if (t == 1) {
    float run = 0.f;
    for (int cc = 0; cc <= NC; ++cc) { preZ[cc] = run; if (cc < NC) run += szN[cc]; }
  }
  __syncthreads();

  // ---- full-resolution scalar denominator tables ----
  {
    int ch = t >> 4;
    float a = 0.f;
    for (int k = t; k < ch * CH + CH; ++k) a += wp[k];
    zps[t] = a + sufZ[ch + 1];
    float b2 = 0.f;
    for (int k = ch * CH; k < t; ++k) b2 += wn[k];
    znp[t] = preZ[ch] + b2;
    if (t == 0) { zps[NA] = 0.f; znp[NA] = preZ[NC]; }
  }
  __syncthreads();

  // ---- per-rank info: thread t = s-rank t (holds vs, is_ in regs) ----
  {
    float A = __expf(vs - amax);
    float B = __expf(NEG * vs - amax);
    float key = -vs;
    int lo = 0, hi = NA;
    while (lo < hi) { int mid = (lo + hi) >> 1; if (tv[mid] < key) lo = mid + 1; else hi = mid; }
    float den = A * zps[lo] + B * znp[lo];
    float4 q; q.x = A; q.y = B; q.z = 1.f / den; q.w = __int_as_float(is_);
    abi[t] = q;
    jsr[t] = lo;
  }
  __syncthreads();

  // ---- E[j]: first rank with jsr <= j (jsr sorted descending) ----
  {
    int lo = 0, hi = NA;
    while (lo < hi) { int mid = (lo + hi) >> 1; if (jsr[mid] > t) lo = mid + 1; else hi = mid; }
    Earr[t] = lo;
  }
  __syncthreads();

  // ---- single ascending sweep with inline emission ----
  {
    float sufPv = sufPc[w * 64 + lane];      // suffix incl. this wave's rows
    float preSeedN = preNc[w * 64 + lane];   // exact prefix before this wave
    float runN = 0.f;
    size_t obase = (size_t)bh * NA * HD + lane;
    int eprev = (w == 0) ? NA : Earr[(w << 6) - 1];   // E[j-1] carried
    #pragma unroll
    for (int jj = 0; jj < 64; ++jj) {
      int j = (w << 6) + jj;
      int ecur = Earr[j];
      float preNv = preSeedN + runN;
      for (int r = ecur; r < eprev; ++r) {   // ranks with js == j
        float4 q = abi[r];
        float x = (q.x * sufPv + q.y * preNv) * q.z;
        int orow = __float_as_int(q.w);
        out[obase + (size_t)orow * HD] = x > 0.f ? x : __expf(x) - 1.f;
      }
      float vv = vreg[jj];
      sufPv -= wp[j] * vv;
      runN  += wn[j] * vv;
      eprev = ecur;
    }
    if (w == NW - 1) {                       // group js == 512: [0, E[511])
      float preNv = preSeedN + runN;         // == total N prefix
      for (int r = 0; r < eprev; ++r) {
        float4 q = abi[r];
        float x = (q.y * preNv) * q.z;       // sufP[512] == 0
        int orow = __float_as_int(q.w);
        out[obase + (size_t)orow * HD] = x > 0.f ? x : __expf(x) - 1.f;
      }
    }
  }
}

extern "C" void kernel_launch(void* const* d_in, const int* in_sizes, int n_in,
                              void* d_out, int out_size, void* d_ws, size_t ws_size,
                              hipStream_t stream) {
  const float* h   = (const float*)d_in[0];
  const float* W   = (const float*)d_in[1];
  const float* att = (const float*)d_in[2];
  float* out = (float*)d_out;
  float* hp    = (float*)d_ws;
  float* s_arr = hp + (size_t)BS * NH * NA * HD;
  float* t_arr = s_arr + (size_t)BS * NH * NA;

  k1_gemm <<<dim3(1024), dim3(256), 0, stream>>>(h, W, att, hp, s_arr, t_arr);
  k2_fused<<<dim3(BS * NH), dim3(512), 0, stream>>>(hp, s_arr, t_arr, out);
}